// Round 13
// baseline (524.796 us; speedup 1.0000x reference)
//
#include <hip/hip_runtime.h>
#include <hip/hip_bf16.h>

#define Nn 100000
#define Ee 1600000
#define Bb 128
#define XD 514        // H2 + P
#define BN_EPS 1e-5f
#define SCAN_NB 196   // ceil(100000/512)
#define NPART 8
#define PART_NODES 12500   // Nn / NPART
#define PART_BLKS 2048     // blocks for partition-pinned kernels (multiple of 8)
#define KC 128             // split-K chunk for head GEMMs
#define NBIN_BLKS 2048
#define CH 784             // edges per bin-block chunk (2048*784 >= Ee)
#define PCAP 212992        // per-partition bin capacity (exp 200K, +31 sigma)

using bf16x8 = __attribute__((ext_vector_type(8))) short;
using f32x4  = __attribute__((ext_vector_type(4))) float;

static __device__ __forceinline__ float grp32_sum(float v){
  v += __shfl_xor(v, 1);
  v += __shfl_xor(v, 2);
  v += __shfl_xor(v, 4);
  v += __shfl_xor(v, 8);
  v += __shfl_xor(v, 16);
  return v;
}

static __device__ __forceinline__ unsigned short f2bf(float f){
  unsigned u = __builtin_bit_cast(unsigned, f);
  unsigned r = (u + 0x7fffu + ((u >> 16) & 1u)) >> 16;
  return (unsigned short)r;
}

static __device__ __forceinline__ float bfl(unsigned u){ return __builtin_bit_cast(float, u << 16); }
static __device__ __forceinline__ float bfh(unsigned u){ return __builtin_bit_cast(float, u & 0xffff0000u); }

// ---------- CSR build via 8-way binning sort ----------
// k_bin: contiguous chunk -> LDS -> per-partition compact lists (burst writes).
// Working set of the later passes then fits one XCD's 4MB L2 (R10 lesson:
// streaming 12.8MB through L2 evicts dirty eidx lines -> 68MB writeback).
__global__ __launch_bounds__(256) void k_bin(const int* __restrict__ src, const int* __restrict__ dst,
                                             int* __restrict__ gCnt, int2* __restrict__ bins){
  __shared__ int sd[CH], ss[CH];
  __shared__ int hist[8], wbase[8], roff[8];
  int t = threadIdx.x;
  if (t < 8){ hist[t] = 0; roff[t] = 0; }
  __syncthreads();
  int e0 = blockIdx.x * CH;
  int e1 = e0 + CH; if (e1 > Ee) e1 = Ee;
  int n = e1 - e0;
  for (int i = t; i < n; i += 256){
    int d = __builtin_nontemporal_load(&dst[e0 + i]);
    int s = __builtin_nontemporal_load(&src[e0 + i]);
    sd[i] = d; ss[i] = s;
    atomicAdd(&hist[d / PART_NODES], 1);
  }
  __syncthreads();
  if (t < 8) wbase[t] = atomicAdd(&gCnt[t], hist[t]);
  __syncthreads();
  for (int i = t; i < n; i += 256){
    int d = sd[i];
    int p = d / PART_NODES;
    int off = atomicAdd(&roff[p], 1);
    bins[(size_t)p * PCAP + wbase[p] + off] = make_int2(d, ss[i]);
  }
}

// count degrees from partition-local compact lists (L2-resident working set)
__global__ __launch_bounds__(256) void k_count2(const int2* __restrict__ bins, const int* __restrict__ gCnt,
                                                int* __restrict__ deg){
  int p = blockIdx.x & (NPART-1);
  int nch = gridDim.x >> 3, chunk = blockIdx.x >> 3;
  int n = gCnt[p];
  const int2* bp = bins + (size_t)p * PCAP;
  for (int i = chunk*256 + threadIdx.x; i < n; i += nch*256){
    atomicAdd(&deg[bp[i].x], 1);
  }
}

__global__ __launch_bounds__(256) void k_scanA(const int* __restrict__ deg, int* __restrict__ bsum){
  __shared__ int red[256];
  int b = blockIdx.x, t = threadIdx.x;
  int i0 = b*512 + t;
  int v = 0;
  if (i0 < Nn) v += deg[i0];
  if (i0 + 256 < Nn) v += deg[i0+256];
  red[t] = v; __syncthreads();
  for (int off=128; off>0; off>>=1){
    if (t < off) red[t] += red[t+off];
    __syncthreads();
  }
  if (t==0) bsum[b] = red[0];
}

__global__ __launch_bounds__(256) void k_scanB(const int* __restrict__ bsum, int* __restrict__ boff,
                                               int* __restrict__ rowptrN, int nb){
  __shared__ int sA[256], sB[256];
  int t = threadIdx.x;
  int own = (t < nb) ? bsum[t] : 0;
  sA[t] = own; __syncthreads();
  int* s = sA; int* d = sB;
  #pragma unroll
  for (int off=1; off<256; off<<=1){
    int x = s[t]; if (t>=off) x += s[t-off];
    d[t] = x; __syncthreads();
    int* tmp = s; s = d; d = tmp;
  }
  int incl = s[t];
  if (t < nb) boff[t] = incl - own;
  if (t == 255) *rowptrN = incl;   // = E
}

__global__ __launch_bounds__(256) void k_scanC(const int* __restrict__ deg, const int* __restrict__ boff,
                                               int* __restrict__ rowptr){
  __shared__ int sA[256], sB[256];
  int b = blockIdx.x, t = threadIdx.x;
  int i0 = b*512 + 2*t;
  int a = (i0 < Nn) ? deg[i0] : 0;
  int c = (i0+1 < Nn) ? deg[i0+1] : 0;
  int s0 = a + c;
  sA[t] = s0; __syncthreads();
  int* s = sA; int* d = sB;
  #pragma unroll
  for (int off=1; off<256; off<<=1){
    int x = s[t]; if (t>=off) x += s[t-off];
    d[t] = x; __syncthreads();
    int* tmp = s; s = d; d = tmp;
  }
  int excl = s[t] - s0 + boff[b];
  if (i0 < Nn)   rowptr[i0]   = excl;
  if (i0+1 < Nn) rowptr[i0+1] = excl + a;
}

// fill eidx from partition-local compact lists
__global__ __launch_bounds__(256) void k_fill2(const int2* __restrict__ bins, const int* __restrict__ gCnt,
                                               int* __restrict__ cur, int* __restrict__ eidx){
  int p = blockIdx.x & (NPART-1);
  int nch = gridDim.x >> 3, chunk = blockIdx.x >> 3;
  int n = gCnt[p];
  const int2* bp = bins + (size_t)p * PCAP;
  for (int i = chunk*256 + threadIdx.x; i < n; i += nch*256){
    int2 e = bp[i];
    int q = atomicAdd(&cur[e.x], 1);
    eidx[q] = e.y;
  }
}

// ---------- GIN layer 1 ----------
__global__ __launch_bounds__(256) void k_gin1(const float* __restrict__ feat, const int* __restrict__ rowptr,
                                              const int* __restrict__ eidx, float* __restrict__ x1){
  int i = blockIdx.x*256 + threadIdx.x;
  if (i >= Nn) return;
  float a0=feat[i*6+0], a1=feat[i*6+1], a2=feat[i*6+2],
        a3=feat[i*6+3], a4=feat[i*6+4], a5=feat[i*6+5];
  int beg = rowptr[i], end = rowptr[i+1];
  for (int j=beg; j<end; ++j){
    const float* f = feat + eidx[j]*6;
    a0+=f[0]; a1+=f[1]; a2+=f[2]; a3+=f[3]; a4+=f[4]; a5+=f[5];
  }
  float* o = x1 + i*6;
  o[0]=a0; o[1]=a1; o[2]=a2; o[3]=a3; o[4]=a4; o[5]=a5;
}

// h1 = relu(x1 @ W0 + b0) stored as bf16   [N,6]->[N,128]
__global__ __launch_bounds__(256) void k_gin1mlp(const float* __restrict__ x1, const float* __restrict__ W0,
                                                 const float* __restrict__ b0, unsigned short* __restrict__ h1){
  __shared__ float sW[768];
  __shared__ float sb[128];
  int t = threadIdx.x;
  for (int i=t; i<768; i+=256) sW[i] = W0[i];
  if (t < 128) sb[t] = b0[t];
  __syncthreads();
  int row = blockIdx.x*2 + (t>>7);
  int c = t & 127;
  if (row >= Nn) return;
  const float* xr = x1 + row*6;
  float acc = sb[c];
  #pragma unroll
  for (int f=0; f<6; ++f) acc += xr[f]*sW[f*128+c];
  h1[row*128+c] = f2bf(fmaxf(acc, 0.f));
}

// ---------- GIN layer 2 neighbor sum: 16 lanes per node, uint4 loads ----------
__global__ __launch_bounds__(256) void k_gather2(const unsigned short* __restrict__ h1,
                                                 const int* __restrict__ rowptr,
                                                 const int* __restrict__ eidx,
                                                 unsigned short* __restrict__ xb){
  int gt = blockIdx.x*256 + threadIdx.x;
  int node = gt >> 4;
  if (node >= Nn) return;
  int l = threadIdx.x & 15;
  int off = l*8;
  float a0,a1,a2,a3,a4,a5,a6,a7;
  {
    uint4 v = *(const uint4*)&h1[(size_t)node*128 + off];
    a0=bfl(v.x); a1=bfh(v.x); a2=bfl(v.y); a3=bfh(v.y);
    a4=bfl(v.z); a5=bfh(v.z); a6=bfl(v.w); a7=bfh(v.w);
  }
  int beg = rowptr[node], end = rowptr[node+1];
  int j = beg;
  for (; j+1 < end; j += 2){
    int s0 = eidx[j], s1 = eidx[j+1];
    uint4 u = *(const uint4*)&h1[(size_t)s0*128 + off];
    uint4 w = *(const uint4*)&h1[(size_t)s1*128 + off];
    a0 += bfl(u.x) + bfl(w.x);
    a1 += bfh(u.x) + bfh(w.x);
    a2 += bfl(u.y) + bfl(w.y);
    a3 += bfh(u.y) + bfh(w.y);
    a4 += bfl(u.z) + bfl(w.z);
    a5 += bfh(u.z) + bfh(w.z);
    a6 += bfl(u.w) + bfl(w.w);
    a7 += bfh(u.w) + bfh(w.w);
  }
  if (j < end){
    uint4 u = *(const uint4*)&h1[(size_t)eidx[j]*128 + off];
    a0 += bfl(u.x); a1 += bfh(u.x);
    a2 += bfl(u.y); a3 += bfh(u.y);
    a4 += bfl(u.z); a5 += bfh(u.z);
    a6 += bfl(u.w); a7 += bfh(u.w);
  }
  uint4 o;
  o.x = (unsigned)f2bf(a0) | ((unsigned)f2bf(a1) << 16);
  o.y = (unsigned)f2bf(a2) | ((unsigned)f2bf(a3) << 16);
  o.z = (unsigned)f2bf(a4) | ((unsigned)f2bf(a5) << 16);
  o.w = (unsigned)f2bf(a6) | ((unsigned)f2bf(a7) << 16);
  *(uint4*)&xb[(size_t)node*128 + off] = o;
}

// ---------- pack W1 [128][512] f32 -> fragment-ordered bf16 ----------
__global__ __launch_bounds__(256) void k_packW(const float* __restrict__ W1, unsigned short* __restrict__ W1p){
  int t = blockIdx.x*256 + threadIdx.x;   // 8192 threads
  int l = t & 63;
  int s = (t >> 6) & 3;
  int f = t >> 8;
  int n = f*16 + (l & 15);
  int kb = s*32 + (l >> 4)*8;
  unsigned short o[8];
  #pragma unroll
  for (int e=0; e<8; ++e) o[e] = f2bf(W1[(kb+e)*512 + n]);
  uint4 pk;
  pk.x = (unsigned)o[0] | ((unsigned)o[1] << 16);
  pk.y = (unsigned)o[2] | ((unsigned)o[3] << 16);
  pk.z = (unsigned)o[4] | ((unsigned)o[5] << 16);
  pk.w = (unsigned)o[6] | ((unsigned)o[7] << 16);
  *(uint4*)&W1p[t*8] = pk;
}

// ---------- GIN2 linear (bf16 MFMA) + relu + fused pooling ----------
// grid (ceil(N/128), 4): block = 128 rows x 128 cols (col quarter = blockIdx.y).
__global__ __launch_bounds__(256) void k_gin2m(const unsigned short* __restrict__ xb,
                                               const unsigned short* __restrict__ W1p,
                                               const float* __restrict__ b1,
                                               const int* __restrict__ gids,
                                               float* __restrict__ pool){
  __shared__ float pool_lds[4][128];
  __shared__ int wgid[4];
  __shared__ int wuni_s[4];
  int w = threadIdx.x >> 6, l = threadIdx.x & 63;
  int wrow = blockIdx.x*128 + w*32;
  int fbase = blockIdx.y * 8;        // 8 f-tiles = 128 cols
  int kbase = (l >> 4) * 8;

  bf16x8 a[2][4];
  #pragma unroll
  for (int r=0; r<2; ++r){
    int arow = wrow + r*16 + (l & 15);
    if (arow > Nn-1) arow = Nn-1;
    const bf16x8* ap = (const bf16x8*)&xb[(size_t)arow*128 + kbase];
    #pragma unroll
    for (int s=0; s<4; ++s) a[r][s] = ap[s*4];
  }

  bool wvalid = wrow < Nn;
  bool wuni = (wrow + 31 < Nn) && (gids[wrow] == gids[wrow + 31]);
  if (l == 0){ wgid[w] = wuni ? gids[wrow] : -1; wuni_s[w] = wuni ? 1 : 0; }

  int rb[2], g0[2];
  bool uval[2];
  #pragma unroll
  for (int r=0; r<2; ++r){
    rb[r] = wrow + r*16 + ((l >> 4) & 3)*4;
    int i0 = rb[r], i3 = rb[r]+3;
    int c0 = i0 < Nn ? i0 : Nn-1;
    int c3 = i3 < Nn ? i3 : Nn-1;
    g0[r] = gids[c0];
    int g3 = gids[c3];
    uval[r] = (i3 < Nn) && (g0[r] == g3);
  }

  float acc_pool[8];
  #pragma unroll
  for (int i=0; i<8; ++i) acc_pool[i] = 0.f;

  const bf16x8* BpAll = (const bf16x8*)W1p;
  bf16x8 bcur[4];
  #pragma unroll
  for (int s=0; s<4; ++s) bcur[s] = BpAll[(fbase*4 + s)*64 + l];

  #pragma unroll
  for (int fi=0; fi<8; ++fi){
    int f = fbase + fi;
    bf16x8 bnext[4];
    if (fi < 7){
      #pragma unroll
      for (int s=0; s<4; ++s) bnext[s] = BpAll[((f+1)*4 + s)*64 + l];
    }
    f32x4 acc0 = {0.f,0.f,0.f,0.f};
    f32x4 acc1 = {0.f,0.f,0.f,0.f};
    #pragma unroll
    for (int s=0; s<4; ++s){
      acc0 = __builtin_amdgcn_mfma_f32_16x16x32_bf16(a[0][s], bcur[s], acc0, 0, 0, 0);
      acc1 = __builtin_amdgcn_mfma_f32_16x16x32_bf16(a[1][s], bcur[s], acc1, 0, 0, 0);
    }
    int col = f*16 + (l & 15);
    float bc = b1[col];
    if (wuni){
      float vsum = 0.f;
      #pragma unroll
      for (int r=0; r<2; ++r){
        f32x4 acc = r ? acc1 : acc0;
        float v = fmaxf(acc[0]+bc, 0.f) + fmaxf(acc[1]+bc, 0.f)
                + fmaxf(acc[2]+bc, 0.f) + fmaxf(acc[3]+bc, 0.f);
        v += __shfl_xor(v, 16);
        v += __shfl_xor(v, 32);
        vsum += v;
      }
      acc_pool[fi] = vsum;
    } else if (wvalid){
      #pragma unroll
      for (int r=0; r<2; ++r){
        f32x4 acc = r ? acc1 : acc0;
        float y0 = fmaxf(acc[0] + bc, 0.f);
        float y1 = fmaxf(acc[1] + bc, 0.f);
        float y2 = fmaxf(acc[2] + bc, 0.f);
        float y3 = fmaxf(acc[3] + bc, 0.f);
        int gg = g0[r];
        int ok = uval[r] ? 1 : 0;
        float v = y0 + y1 + y2 + y3;
        int gX  = __shfl_xor(gg, 16);
        int okX = __shfl_xor(ok, 16);
        ok = ok & okX & (gg == gX ? 1 : 0);
        float v2 = v + __shfl_xor(v, 16);
        int gY  = __shfl_xor(gg, 32);
        int okY = __shfl_xor(ok, 32);
        float v4 = v2 + __shfl_xor(v2, 32);
        ok = ok & okY & (gg == gY ? 1 : 0);
        if (ok){
          if (l < 16) atomicAdd(&pool[gg*XD + col], v4);
        } else {
          int base = rb[r];
          if (base   < Nn) atomicAdd(&pool[gids[base  ]*XD + col], y0);
          if (base+1 < Nn) atomicAdd(&pool[gids[base+1]*XD + col], y1);
          if (base+2 < Nn) atomicAdd(&pool[gids[base+2]*XD + col], y2);
          if (base+3 < Nn) atomicAdd(&pool[gids[base+3]*XD + col], y3);
        }
      }
    }
    if (fi < 7){
      #pragma unroll
      for (int s=0; s<4; ++s) bcur[s] = bnext[s];
    }
  }

  if (wuni && l < 16){
    #pragma unroll
    for (int fi=0; fi<8; ++fi) pool_lds[w][fi*16 + l] = acc_pool[fi];
  }
  __syncthreads();
  int t = threadIdx.x;
  if (t < 128){
    int cg = -1; float s = 0.f;
    #pragma unroll
    for (int ww=0; ww<4; ++ww){
      if (!wuni_s[ww]) continue;
      int g = wgid[ww];
      if (g != cg){
        if (cg >= 0) atomicAdd(&pool[cg*XD + fbase*16 + t], s);
        cg = g; s = 0.f;
      }
      s += pool_lds[ww][t];
    }
    if (cg >= 0) atomicAdd(&pool[cg*XD + fbase*16 + t], s);
  }
}

// ---------- prompt head ----------
__global__ void k_pr(const float* __restrict__ prompt, const float* __restrict__ Wp,
                     const float* __restrict__ bp, float* __restrict__ xmlp){
  int t = threadIdx.x;
  if (t < 256){
    int r = t>>1, j = t&1;
    float v = prompt[r*2+0]*Wp[0*2+j] + prompt[r*2+1]*Wp[1*2+j] + bp[j];
    xmlp[r*XD + 512 + j] = v;
  }
}

// ---------- head GEMM, split-K: Zp[z][128][NC] = X[.,k0:k0+KC] @ W[k0:k0+KC,.] ----------
__global__ __launch_bounds__(256) void k_lin(const float* __restrict__ X, const float* __restrict__ W,
                                             float* __restrict__ Zp, int K, int NC){
  __shared__ float xT[16][KC];
  int c = blockIdx.x*256 + threadIdx.x;
  int row0 = blockIdx.y*16;
  int k0 = blockIdx.z*KC;
  int kn = K - k0; if (kn > KC) kn = KC;
  if (kn == KC){
    int r = threadIdx.x >> 7;          // 2 rows per pass, 8 passes
    int kk = threadIdx.x & 127;
    #pragma unroll
    for (int i=0; i<8; ++i) xT[r + i*2][kk] = X[(size_t)(row0 + r + i*2)*K + k0 + kk];
  } else {
    for (int idx = threadIdx.x; idx < 16*kn; idx += 256){
      int r = idx / kn, kk = idx - r*kn;
      xT[r][kk] = X[(size_t)(row0+r)*K + k0 + kk];
    }
  }
  __syncthreads();
  float acc[16];
  #pragma unroll
  for (int r=0; r<16; ++r) acc[r] = 0.f;
  for (int kk=0; kk<kn; ++kk){
    float w = W[(size_t)(k0+kk)*NC + c];
    #pragma unroll
    for (int r=0; r<16; ++r) acc[r] += xT[r][kk]*w;
  }
  float* Zb = Zp + (size_t)blockIdx.z*128*NC;
  #pragma unroll
  for (int r=0; r<16; ++r) Zb[(size_t)(row0+r)*NC + c] = acc[r];
}

// ---------- reduce split-K partials + bias + BatchNorm + ReLU ----------
__global__ __launch_bounds__(256) void k_bnrelu(const float* __restrict__ Zp, const float* __restrict__ bias,
                                                const float* __restrict__ gamma, const float* __restrict__ beta,
                                                float* __restrict__ Y, int NC, int nk){
  int grp = threadIdx.x>>5, l32 = threadIdx.x&31;
  int col = blockIdx.x*8 + grp;
  int r0 = l32*4;
  float z0=0.f, z1=0.f, z2=0.f, z3=0.f;
  for (int j=0; j<nk; ++j){
    const float* Zb = Zp + (size_t)j*128*NC + col;
    z0 += Zb[(size_t)(r0+0)*NC];
    z1 += Zb[(size_t)(r0+1)*NC];
    z2 += Zb[(size_t)(r0+2)*NC];
    z3 += Zb[(size_t)(r0+3)*NC];
  }
  float bc = bias[col];
  z0+=bc; z1+=bc; z2+=bc; z3+=bc;
  float mean = grp32_sum(z0+z1+z2+z3) * (1.f/128.f);
  float d0=z0-mean, d1=z1-mean, d2=z2-mean, d3=z3-mean;
  float var = grp32_sum(d0*d0+d1*d1+d2*d2+d3*d3) * (1.f/128.f);
  float sc = gamma[col]*rsqrtf(var + BN_EPS);
  float bt = beta[col];
  Y[(size_t)(r0+0)*NC+col] = fmaxf(d0*sc+bt, 0.f);
  Y[(size_t)(r0+1)*NC+col] = fmaxf(d1*sc+bt, 0.f);
  Y[(size_t)(r0+2)*NC+col] = fmaxf(d2*sc+bt, 0.f);
  Y[(size_t)(r0+3)*NC+col] = fmaxf(d3*sc+bt, 0.f);
}

// ---------- output layer: block per row, row staged in LDS, coalesced W2 ----------
__global__ __launch_bounds__(128) void k_out(const float* __restrict__ y1, const float* __restrict__ W2,
                                             const float* __restrict__ b2, float* __restrict__ out){
  __shared__ float yr[512];
  int r = blockIdx.x;
  for (int k=threadIdx.x; k<512; k+=128) yr[k] = y1[r*512+k];
  __syncthreads();
  int c = threadIdx.x;
  if (c < 100){
    float a0=0.f, a1=0.f, a2=0.f, a3=0.f;
    for (int k=0; k<512; k+=4){
      a0 += yr[k+0]*W2[(k+0)*100+c];
      a1 += yr[k+1]*W2[(k+1)*100+c];
      a2 += yr[k+2]*W2[(k+2)*100+c];
      a3 += yr[k+3]*W2[(k+3)*100+c];
    }
    out[r*100+c] = b2[c] + ((a0+a1)+(a2+a3));
  }
}

extern "C" void kernel_launch(void* const* d_in, const int* in_sizes, int n_in,
                              void* d_out, int out_size, void* d_ws, size_t ws_size,
                              hipStream_t stream)
{
  const float* feat   = (const float*)d_in[0];
  const float* prompt = (const float*)d_in[1];
  const int*   src    = (const int*)d_in[2];
  const int*   dst    = (const int*)d_in[3];
  const int*   gids   = (const int*)d_in[4];
  const float* W0  = (const float*)d_in[5];
  const float* b0  = (const float*)d_in[6];
  const float* W1  = (const float*)d_in[7];
  const float* b1  = (const float*)d_in[8];
  const float* Wp  = (const float*)d_in[9];
  const float* bp  = (const float*)d_in[10];
  const float* Wm0 = (const float*)d_in[11];
  const float* bm0 = (const float*)d_in[12];
  const float* g0  = (const float*)d_in[13];
  const float* be0 = (const float*)d_in[14];
  const float* Wm1 = (const float*)d_in[15];
  const float* bm1 = (const float*)d_in[16];
  const float* g1  = (const float*)d_in[17];
  const float* be1 = (const float*)d_in[18];
  const float* Wm2 = (const float*)d_in[19];
  const float* bm2 = (const float*)d_in[20];
  float* out = (float*)d_out;

  char* p = (char*)d_ws;
  auto carve = [&](size_t bytes) -> void* {
    void* r = (void*)p;
    p += (bytes + 255) & ~(size_t)255;
    return r;
  };
  int*   deg    = (int*)carve((size_t)Nn*4);
  int*   rowptr = (int*)carve((size_t)(Nn+1)*4);
  int*   cur    = (int*)carve((size_t)Nn*4);
  int*   bsum   = (int*)carve(256*4);
  int*   boff   = (int*)carve(256*4);
  int*   gCnt   = (int*)carve(256*4);
  int*   eidx   = (int*)carve((size_t)Ee*4);
  float* x1     = (float*)carve((size_t)Nn*6*4);
  unsigned short* h1  = (unsigned short*)carve((size_t)Nn*128*2);
  unsigned short* xb  = (unsigned short*)carve((size_t)Nn*128*2);
  unsigned short* W1p = (unsigned short*)carve((size_t)128*512*2);
  float* xmlp   = (float*)carve((size_t)Bb*XD*4);
  float* y0     = (float*)carve((size_t)Bb*1024*4);
  float* y1     = (float*)carve((size_t)Bb*512*4);

  // aliases onto dead regions:
  // bins: 8*PCAP*8B = 13.6MB into h1 (25.6MB; h1 first written AFTER k_fill2)
  // Zp0/Zp1: split-K partials into eidx/x1 (dead once the head runs)
  int2*  bins = (int2*)h1;
  float* Zp0 = (float*)eidx;
  float* Zp1 = (float*)x1;

  hipMemsetAsync(deg, 0, (size_t)Nn*4, stream);
  hipMemsetAsync(gCnt, 0, 8*4, stream);
  hipMemsetAsync(xmlp, 0, (size_t)Bb*XD*4, stream);

  k_packW<<<32, 256, 0, stream>>>(W1, W1p);

  k_bin<<<NBIN_BLKS, 256, 0, stream>>>(src, dst, gCnt, bins);
  k_count2<<<PART_BLKS, 256, 0, stream>>>(bins, gCnt, deg);
  k_scanA<<<SCAN_NB, 256, 0, stream>>>(deg, bsum);
  k_scanB<<<1, 256, 0, stream>>>(bsum, boff, rowptr + Nn, SCAN_NB);
  k_scanC<<<SCAN_NB, 256, 0, stream>>>(deg, boff, rowptr);
  hipMemcpyAsync(cur, rowptr, (size_t)Nn*4, hipMemcpyDeviceToDevice, stream);
  k_fill2<<<PART_BLKS, 256, 0, stream>>>(bins, gCnt, cur, eidx);

  k_gin1<<<(Nn+255)/256, 256, 0, stream>>>(feat, rowptr, eidx, x1);
  k_gin1mlp<<<Nn/2, 256, 0, stream>>>(x1, W0, b0, h1);

  k_gather2<<<(Nn*16+255)/256, 256, 0, stream>>>(h1, rowptr, eidx, xb);
  dim3 g2((Nn+127)/128, 4);
  k_gin2m<<<g2, 256, 0, stream>>>(xb, W1p, b1, gids, xmlp);

  k_pr<<<1, 256, 0, stream>>>(prompt, Wp, bp, xmlp);

  // MLP head: split-K GEMM + fused BN/ReLU reduce
  dim3 gl0(1024/256, 8, (XD + KC - 1)/KC);      // (4, 8, 5)
  k_lin<<<gl0, 256, 0, stream>>>(xmlp, Wm0, Zp0, XD, 1024);
  k_bnrelu<<<1024/8, 256, 0, stream>>>(Zp0, bm0, g0, be0, y0, 1024, (XD + KC - 1)/KC);

  dim3 gl1(512/256, 8, 1024/KC);                // (2, 8, 8)
  k_lin<<<gl1, 256, 0, stream>>>(y0, Wm1, Zp1, 1024, 512);
  k_bnrelu<<<512/8, 256, 0, stream>>>(Zp1, bm1, g1, be1, y1, 512, 1024/KC);

  k_out<<<Bb, 128, 0, stream>>>(y1, Wm2, bm2, out);
}

// Round 15
// 436.848 us; speedup vs baseline: 1.2013x; 1.2013x over previous
//
#include <hip/hip_runtime.h>
#include <hip/hip_bf16.h>

#define Nn 100000
#define Ee 1600000
#define Bb 128
#define XD 514        // H2 + P
#define BN_EPS 1e-5f
#define SCAN_NB 196   // ceil(100000/512)
#define KC 128        // split-K chunk for head GEMMs
#define NBIN_BLKS 2048
#define CH 784        // edges per bin-block chunk (2048*784 >= Ee)
#define NBINS2 131    // ceil(100000/768)
#define BINN 768      // nodes per bin
#define PCAP2 13312   // per-bin capacity (exp 12288, +9 sigma)

using bf16x8 = __attribute__((ext_vector_type(8))) short;
using f32x4  = __attribute__((ext_vector_type(4))) float;

static __device__ __forceinline__ float grp32_sum(float v){
  v += __shfl_xor(v, 1);
  v += __shfl_xor(v, 2);
  v += __shfl_xor(v, 4);
  v += __shfl_xor(v, 8);
  v += __shfl_xor(v, 16);
  return v;
}

static __device__ __forceinline__ unsigned short f2bf(float f){
  unsigned u = __builtin_bit_cast(unsigned, f);
  unsigned r = (u + 0x7fffu + ((u >> 16) & 1u)) >> 16;
  return (unsigned short)r;
}

static __device__ __forceinline__ float bfl(unsigned u){ return __builtin_bit_cast(float, u << 16); }
static __device__ __forceinline__ float bfh(unsigned u){ return __builtin_bit_cast(float, u & 0xffff0000u); }

// ---------- CSR build via in-LDS counting sort (R13 lesson: gfx950 L2 does not
// write-allocate scattered stores -> every 4B scatter = partial-line HBM RMW.
// All global writes below are sorted-contiguous so waves emit full lines.) ----------

// k_bin2: chunk -> LDS -> 131-way in-LDS counting sort -> contiguous segment writes
__global__ __launch_bounds__(256) void k_bin2(const int* __restrict__ src, const int* __restrict__ dst,
                                              int* __restrict__ gCnt, int2* __restrict__ bins){
  __shared__ int sd[CH], ss[CH], od[CH], os[CH];
  __shared__ int hist[NBINS2], wbase[NBINS2], roff[NBINS2], lbase[NBINS2];
  __shared__ int sA[256], sBv[256];
  int t = threadIdx.x;
  for (int b=t; b<NBINS2; b+=256){ hist[b]=0; roff[b]=0; }
  __syncthreads();
  int e0 = blockIdx.x * CH;
  int e1 = e0 + CH; if (e1 > Ee) e1 = Ee;
  int n = e1 - e0;
  for (int i=t; i<n; i+=256){
    int d = __builtin_nontemporal_load(&dst[e0+i]);
    int s = __builtin_nontemporal_load(&src[e0+i]);
    sd[i]=d; ss[i]=s;
    atomicAdd(&hist[d/BINN], 1);
  }
  __syncthreads();
  int own = (t < NBINS2) ? hist[t] : 0;
  sA[t] = own; __syncthreads();
  int* sp = sA; int* dp = sBv;
  #pragma unroll
  for (int off=1; off<256; off<<=1){
    int x = sp[t]; if (t>=off) x += sp[t-off];
    dp[t] = x; __syncthreads();
    int* tmp = sp; sp = dp; dp = tmp;
  }
  if (t < NBINS2){
    lbase[t] = sp[t] - own;
    if (own > 0) wbase[t] = atomicAdd(&gCnt[t], own);
  }
  __syncthreads();
  for (int i=t; i<n; i+=256){
    int d = sd[i];
    int b = d / BINN;
    int loc = atomicAdd(&roff[b], 1);
    int pos = lbase[b] + loc;
    od[pos] = d; os[pos] = ss[i];
  }
  __syncthreads();
  for (int i=t; i<n; i+=256){
    int d = od[i];
    int b = d / BINN;
    bins[(size_t)b*PCAP2 + wbase[b] + (i - lbase[b])] = make_int2(d, os[i]);
  }
}

// k_deg: per-bin LDS histogram -> contiguous deg writes
__global__ __launch_bounds__(256) void k_deg(const int2* __restrict__ bins, const int* __restrict__ gCnt,
                                             int* __restrict__ deg){
  __shared__ int lhist[BINN];
  int b = blockIdx.x;
  int nb = b*BINN;
  int nn = Nn - nb; if (nn > BINN) nn = BINN;
  int t = threadIdx.x;
  for (int j=t; j<nn; j+=256) lhist[j]=0;
  __syncthreads();
  int n = gCnt[b];
  const int2* bp = bins + (size_t)b*PCAP2;
  for (int i=t; i<n; i+=256) atomicAdd(&lhist[bp[i].x - nb], 1);
  __syncthreads();
  for (int j=t; j<nn; j+=256) deg[nb+j] = lhist[j];
}

__global__ __launch_bounds__(256) void k_scanA(const int* __restrict__ deg, int* __restrict__ bsum){
  __shared__ int red[256];
  int b = blockIdx.x, t = threadIdx.x;
  int i0 = b*512 + t;
  int v = 0;
  if (i0 < Nn) v += deg[i0];
  if (i0 + 256 < Nn) v += deg[i0+256];
  red[t] = v; __syncthreads();
  for (int off=128; off>0; off>>=1){
    if (t < off) red[t] += red[t+off];
    __syncthreads();
  }
  if (t==0) bsum[b] = red[0];
}

__global__ __launch_bounds__(256) void k_scanB(const int* __restrict__ bsum, int* __restrict__ boff,
                                               int* __restrict__ rowptrN, int nb){
  __shared__ int sA[256], sB[256];
  int t = threadIdx.x;
  int own = (t < nb) ? bsum[t] : 0;
  sA[t] = own; __syncthreads();
  int* s = sA; int* d = sB;
  #pragma unroll
  for (int off=1; off<256; off<<=1){
    int x = s[t]; if (t>=off) x += s[t-off];
    d[t] = x; __syncthreads();
    int* tmp = s; s = d; d = tmp;
  }
  int incl = s[t];
  if (t < nb) boff[t] = incl - own;
  if (t == 255) *rowptrN = incl;   // = E
}

__global__ __launch_bounds__(256) void k_scanC(const int* __restrict__ deg, const int* __restrict__ boff,
                                               int* __restrict__ rowptr){
  __shared__ int sA[256], sB[256];
  int b = blockIdx.x, t = threadIdx.x;
  int i0 = b*512 + 2*t;
  int a = (i0 < Nn) ? deg[i0] : 0;
  int c = (i0+1 < Nn) ? deg[i0+1] : 0;
  int s0 = a + c;
  sA[t] = s0; __syncthreads();
  int* s = sA; int* d = sB;
  #pragma unroll
  for (int off=1; off<256; off<<=1){
    int x = s[t]; if (t>=off) x += s[t-off];
    d[t] = x; __syncthreads();
    int* tmp = s; s = d; d = tmp;
  }
  int excl = s[t] - s0 + boff[b];
  if (i0 < Nn)   rowptr[i0]   = excl;
  if (i0+1 < Nn) rowptr[i0+1] = excl + a;
}

// k_sort: bin list -> LDS counting-sorted segment -> contiguous eidx writes
__global__ __launch_bounds__(256) void k_sort(const int2* __restrict__ bins, const int* __restrict__ gCnt,
                                              const int* __restrict__ rowptr, int* __restrict__ eidx){
  __shared__ int lrp[BINN+1];
  __shared__ int cnt[BINN];
  __shared__ int sorted[PCAP2];
  int b = blockIdx.x;
  int nb = b*BINN;
  int nn = Nn - nb; if (nn > BINN) nn = BINN;
  int t = threadIdx.x;
  for (int j=t; j<=nn; j+=256) lrp[j] = rowptr[nb+j];
  for (int j=t; j<nn; j+=256) cnt[j] = 0;
  __syncthreads();
  int base0 = lrp[0];
  int n = gCnt[b];
  const int2* bp = bins + (size_t)b*PCAP2;
  for (int i=t; i<n; i+=256){
    int2 e = bp[i];
    int dl = e.x - nb;
    int pos = lrp[dl] - base0 + atomicAdd(&cnt[dl], 1);
    sorted[pos] = e.y;
  }
  __syncthreads();
  for (int i=t; i<n; i+=256) eidx[base0+i] = sorted[i];
}

// ---------- GIN layer 1 ----------
__global__ __launch_bounds__(256) void k_gin1(const float* __restrict__ feat, const int* __restrict__ rowptr,
                                              const int* __restrict__ eidx, float* __restrict__ x1){
  int i = blockIdx.x*256 + threadIdx.x;
  if (i >= Nn) return;
  float a0=feat[i*6+0], a1=feat[i*6+1], a2=feat[i*6+2],
        a3=feat[i*6+3], a4=feat[i*6+4], a5=feat[i*6+5];
  int beg = rowptr[i], end = rowptr[i+1];
  for (int j=beg; j<end; ++j){
    const float* f = feat + eidx[j]*6;
    a0+=f[0]; a1+=f[1]; a2+=f[2]; a3+=f[3]; a4+=f[4]; a5+=f[5];
  }
  float* o = x1 + i*6;
  o[0]=a0; o[1]=a1; o[2]=a2; o[3]=a3; o[4]=a4; o[5]=a5;
}

// h1 = relu(x1 @ W0 + b0) stored as bf16   [N,6]->[N,128]
__global__ __launch_bounds__(256) void k_gin1mlp(const float* __restrict__ x1, const float* __restrict__ W0,
                                                 const float* __restrict__ b0, unsigned short* __restrict__ h1){
  __shared__ float sW[768];
  __shared__ float sb[128];
  int t = threadIdx.x;
  for (int i=t; i<768; i+=256) sW[i] = W0[i];
  if (t < 128) sb[t] = b0[t];
  __syncthreads();
  int row = blockIdx.x*2 + (t>>7);
  int c = t & 127;
  if (row >= Nn) return;
  const float* xr = x1 + row*6;
  float acc = sb[c];
  #pragma unroll
  for (int f=0; f<6; ++f) acc += xr[f]*sW[f*128+c];
  h1[row*128+c] = f2bf(fmaxf(acc, 0.f));
}

// ---------- GIN layer 2 neighbor sum: 16 lanes per node, uint4 loads ----------
__global__ __launch_bounds__(256) void k_gather2(const unsigned short* __restrict__ h1,
                                                 const int* __restrict__ rowptr,
                                                 const int* __restrict__ eidx,
                                                 unsigned short* __restrict__ xb){
  int gt = blockIdx.x*256 + threadIdx.x;
  int node = gt >> 4;
  if (node >= Nn) return;
  int l = threadIdx.x & 15;
  int off = l*8;
  float a0,a1,a2,a3,a4,a5,a6,a7;
  {
    uint4 v = *(const uint4*)&h1[(size_t)node*128 + off];
    a0=bfl(v.x); a1=bfh(v.x); a2=bfl(v.y); a3=bfh(v.y);
    a4=bfl(v.z); a5=bfh(v.z); a6=bfl(v.w); a7=bfh(v.w);
  }
  int beg = rowptr[node], end = rowptr[node+1];
  int j = beg;
  for (; j+1 < end; j += 2){
    int s0 = eidx[j], s1 = eidx[j+1];
    uint4 u = *(const uint4*)&h1[(size_t)s0*128 + off];
    uint4 w = *(const uint4*)&h1[(size_t)s1*128 + off];
    a0 += bfl(u.x) + bfl(w.x);
    a1 += bfh(u.x) + bfh(w.x);
    a2 += bfl(u.y) + bfl(w.y);
    a3 += bfh(u.y) + bfh(w.y);
    a4 += bfl(u.z) + bfl(w.z);
    a5 += bfh(u.z) + bfh(w.z);
    a6 += bfl(u.w) + bfl(w.w);
    a7 += bfh(u.w) + bfh(w.w);
  }
  if (j < end){
    uint4 u = *(const uint4*)&h1[(size_t)eidx[j]*128 + off];
    a0 += bfl(u.x); a1 += bfh(u.x);
    a2 += bfl(u.y); a3 += bfh(u.y);
    a4 += bfl(u.z); a5 += bfh(u.z);
    a6 += bfl(u.w); a7 += bfh(u.w);
  }
  uint4 o;
  o.x = (unsigned)f2bf(a0) | ((unsigned)f2bf(a1) << 16);
  o.y = (unsigned)f2bf(a2) | ((unsigned)f2bf(a3) << 16);
  o.z = (unsigned)f2bf(a4) | ((unsigned)f2bf(a5) << 16);
  o.w = (unsigned)f2bf(a6) | ((unsigned)f2bf(a7) << 16);
  *(uint4*)&xb[(size_t)node*128 + off] = o;
}

// ---------- pack W1 [128][512] f32 -> fragment-ordered bf16 ----------
__global__ __launch_bounds__(256) void k_packW(const float* __restrict__ W1, unsigned short* __restrict__ W1p){
  int t = blockIdx.x*256 + threadIdx.x;   // 8192 threads
  int l = t & 63;
  int s = (t >> 6) & 3;
  int f = t >> 8;
  int n = f*16 + (l & 15);
  int kb = s*32 + (l >> 4)*8;
  unsigned short o[8];
  #pragma unroll
  for (int e=0; e<8; ++e) o[e] = f2bf(W1[(kb+e)*512 + n]);
  uint4 pk;
  pk.x = (unsigned)o[0] | ((unsigned)o[1] << 16);
  pk.y = (unsigned)o[2] | ((unsigned)o[3] << 16);
  pk.z = (unsigned)o[4] | ((unsigned)o[5] << 16);
  pk.w = (unsigned)o[6] | ((unsigned)o[7] << 16);
  *(uint4*)&W1p[t*8] = pk;
}

// ---------- GIN2 linear (bf16 MFMA) + relu + fused pooling ----------
// grid (ceil(N/128), 4): block = 128 rows x 128 cols (col quarter = blockIdx.y).
__global__ __launch_bounds__(256) void k_gin2m(const unsigned short* __restrict__ xb,
                                               const unsigned short* __restrict__ W1p,
                                               const float* __restrict__ b1,
                                               const int* __restrict__ gids,
                                               float* __restrict__ pool){
  __shared__ float pool_lds[4][128];
  __shared__ int wgid[4];
  __shared__ int wuni_s[4];
  int w = threadIdx.x >> 6, l = threadIdx.x & 63;
  int wrow = blockIdx.x*128 + w*32;
  int fbase = blockIdx.y * 8;        // 8 f-tiles = 128 cols
  int kbase = (l >> 4) * 8;

  bf16x8 a[2][4];
  #pragma unroll
  for (int r=0; r<2; ++r){
    int arow = wrow + r*16 + (l & 15);
    if (arow > Nn-1) arow = Nn-1;
    const bf16x8* ap = (const bf16x8*)&xb[(size_t)arow*128 + kbase];
    #pragma unroll
    for (int s=0; s<4; ++s) a[r][s] = ap[s*4];
  }

  bool wvalid = wrow < Nn;
  bool wuni = (wrow + 31 < Nn) && (gids[wrow] == gids[wrow + 31]);
  if (l == 0){ wgid[w] = wuni ? gids[wrow] : -1; wuni_s[w] = wuni ? 1 : 0; }

  int rb[2], g0[2];
  bool uval[2];
  #pragma unroll
  for (int r=0; r<2; ++r){
    rb[r] = wrow + r*16 + ((l >> 4) & 3)*4;
    int i0 = rb[r], i3 = rb[r]+3;
    int c0 = i0 < Nn ? i0 : Nn-1;
    int c3 = i3 < Nn ? i3 : Nn-1;
    g0[r] = gids[c0];
    int g3 = gids[c3];
    uval[r] = (i3 < Nn) && (g0[r] == g3);
  }

  float acc_pool[8];
  #pragma unroll
  for (int i=0; i<8; ++i) acc_pool[i] = 0.f;

  const bf16x8* BpAll = (const bf16x8*)W1p;
  bf16x8 bcur[4];
  #pragma unroll
  for (int s=0; s<4; ++s) bcur[s] = BpAll[(fbase*4 + s)*64 + l];

  #pragma unroll
  for (int fi=0; fi<8; ++fi){
    int f = fbase + fi;
    bf16x8 bnext[4];
    if (fi < 7){
      #pragma unroll
      for (int s=0; s<4; ++s) bnext[s] = BpAll[((f+1)*4 + s)*64 + l];
    }
    f32x4 acc0 = {0.f,0.f,0.f,0.f};
    f32x4 acc1 = {0.f,0.f,0.f,0.f};
    #pragma unroll
    for (int s=0; s<4; ++s){
      acc0 = __builtin_amdgcn_mfma_f32_16x16x32_bf16(a[0][s], bcur[s], acc0, 0, 0, 0);
      acc1 = __builtin_amdgcn_mfma_f32_16x16x32_bf16(a[1][s], bcur[s], acc1, 0, 0, 0);
    }
    int col = f*16 + (l & 15);
    float bc = b1[col];
    if (wuni){
      float vsum = 0.f;
      #pragma unroll
      for (int r=0; r<2; ++r){
        f32x4 acc = r ? acc1 : acc0;
        float v = fmaxf(acc[0]+bc, 0.f) + fmaxf(acc[1]+bc, 0.f)
                + fmaxf(acc[2]+bc, 0.f) + fmaxf(acc[3]+bc, 0.f);
        v += __shfl_xor(v, 16);
        v += __shfl_xor(v, 32);
        vsum += v;
      }
      acc_pool[fi] = vsum;
    } else if (wvalid){
      #pragma unroll
      for (int r=0; r<2; ++r){
        f32x4 acc = r ? acc1 : acc0;
        float y0 = fmaxf(acc[0] + bc, 0.f);
        float y1 = fmaxf(acc[1] + bc, 0.f);
        float y2 = fmaxf(acc[2] + bc, 0.f);
        float y3 = fmaxf(acc[3] + bc, 0.f);
        int gg = g0[r];
        int ok = uval[r] ? 1 : 0;
        float v = y0 + y1 + y2 + y3;
        int gX  = __shfl_xor(gg, 16);
        int okX = __shfl_xor(ok, 16);
        ok = ok & okX & (gg == gX ? 1 : 0);
        float v2 = v + __shfl_xor(v, 16);
        int gY  = __shfl_xor(gg, 32);
        int okY = __shfl_xor(ok, 32);
        float v4 = v2 + __shfl_xor(v2, 32);
        ok = ok & okY & (gg == gY ? 1 : 0);
        if (ok){
          if (l < 16) atomicAdd(&pool[gg*XD + col], v4);
        } else {
          int base = rb[r];
          if (base   < Nn) atomicAdd(&pool[gids[base  ]*XD + col], y0);
          if (base+1 < Nn) atomicAdd(&pool[gids[base+1]*XD + col], y1);
          if (base+2 < Nn) atomicAdd(&pool[gids[base+2]*XD + col], y2);
          if (base+3 < Nn) atomicAdd(&pool[gids[base+3]*XD + col], y3);
        }
      }
    }
    if (fi < 7){
      #pragma unroll
      for (int s=0; s<4; ++s) bcur[s] = bnext[s];
    }
  }

  if (wuni && l < 16){
    #pragma unroll
    for (int fi=0; fi<8; ++fi) pool_lds[w][fi*16 + l] = acc_pool[fi];
  }
  __syncthreads();
  int t = threadIdx.x;
  if (t < 128){
    int cg = -1; float s = 0.f;
    #pragma unroll
    for (int ww=0; ww<4; ++ww){
      if (!wuni_s[ww]) continue;
      int g = wgid[ww];
      if (g != cg){
        if (cg >= 0) atomicAdd(&pool[cg*XD + fbase*16 + t], s);
        cg = g; s = 0.f;
      }
      s += pool_lds[ww][t];
    }
    if (cg >= 0) atomicAdd(&pool[cg*XD + fbase*16 + t], s);
  }
}

// ---------- prompt head ----------
__global__ void k_pr(const float* __restrict__ prompt, const float* __restrict__ Wp,
                     const float* __restrict__ bp, float* __restrict__ xmlp){
  int t = threadIdx.x;
  if (t < 256){
    int r = t>>1, j = t&1;
    float v = prompt[r*2+0]*Wp[0*2+j] + prompt[r*2+1]*Wp[1*2+j] + bp[j];
    xmlp[r*XD + 512 + j] = v;
  }
}

// ---------- head GEMM, split-K: Zp[z][128][NC] = X[.,k0:k0+KC] @ W[k0:k0+KC,.] ----------
__global__ __launch_bounds__(256) void k_lin(const float* __restrict__ X, const float* __restrict__ W,
                                             float* __restrict__ Zp, int K, int NC){
  __shared__ float xT[16][KC];
  int c = blockIdx.x*256 + threadIdx.x;
  int row0 = blockIdx.y*16;
  int k0 = blockIdx.z*KC;
  int kn = K - k0; if (kn > KC) kn = KC;
  if (kn == KC){
    int r = threadIdx.x >> 7;          // 2 rows per pass, 8 passes
    int kk = threadIdx.x & 127;
    #pragma unroll
    for (int i=0; i<8; ++i) xT[r + i*2][kk] = X[(size_t)(row0 + r + i*2)*K + k0 + kk];
  } else {
    for (int idx = threadIdx.x; idx < 16*kn; idx += 256){
      int r = idx / kn, kk = idx - r*kn;
      xT[r][kk] = X[(size_t)(row0+r)*K + k0 + kk];
    }
  }
  __syncthreads();
  float acc[16];
  #pragma unroll
  for (int r=0; r<16; ++r) acc[r] = 0.f;
  for (int kk=0; kk<kn; ++kk){
    float w = W[(size_t)(k0+kk)*NC + c];
    #pragma unroll
    for (int r=0; r<16; ++r) acc[r] += xT[r][kk]*w;
  }
  float* Zb = Zp + (size_t)blockIdx.z*128*NC;
  #pragma unroll
  for (int r=0; r<16; ++r) Zb[(size_t)(row0+r)*NC + c] = acc[r];
}

// ---------- reduce split-K partials + bias + BatchNorm + ReLU ----------
__global__ __launch_bounds__(256) void k_bnrelu(const float* __restrict__ Zp, const float* __restrict__ bias,
                                                const float* __restrict__ gamma, const float* __restrict__ beta,
                                                float* __restrict__ Y, int NC, int nk){
  int grp = threadIdx.x>>5, l32 = threadIdx.x&31;
  int col = blockIdx.x*8 + grp;
  int r0 = l32*4;
  float z0=0.f, z1=0.f, z2=0.f, z3=0.f;
  for (int j=0; j<nk; ++j){
    const float* Zb = Zp + (size_t)j*128*NC + col;
    z0 += Zb[(size_t)(r0+0)*NC];
    z1 += Zb[(size_t)(r0+1)*NC];
    z2 += Zb[(size_t)(r0+2)*NC];
    z3 += Zb[(size_t)(r0+3)*NC];
  }
  float bc = bias[col];
  z0+=bc; z1+=bc; z2+=bc; z3+=bc;
  float mean = grp32_sum(z0+z1+z2+z3) * (1.f/128.f);
  float d0=z0-mean, d1=z1-mean, d2=z2-mean, d3=z3-mean;
  float var = grp32_sum(d0*d0+d1*d1+d2*d2+d3*d3) * (1.f/128.f);
  float sc = gamma[col]*rsqrtf(var + BN_EPS);
  float bt = beta[col];
  Y[(size_t)(r0+0)*NC+col] = fmaxf(d0*sc+bt, 0.f);
  Y[(size_t)(r0+1)*NC+col] = fmaxf(d1*sc+bt, 0.f);
  Y[(size_t)(r0+2)*NC+col] = fmaxf(d2*sc+bt, 0.f);
  Y[(size_t)(r0+3)*NC+col] = fmaxf(d3*sc+bt, 0.f);
}

// ---------- output layer: block per row, row staged in LDS, coalesced W2 ----------
__global__ __launch_bounds__(128) void k_out(const float* __restrict__ y1, const float* __restrict__ W2,
                                             const float* __restrict__ b2, float* __restrict__ out){
  __shared__ float yr[512];
  int r = blockIdx.x;
  for (int k=threadIdx.x; k<512; k+=128) yr[k] = y1[r*512+k];
  __syncthreads();
  int c = threadIdx.x;
  if (c < 100){
    float a0=0.f, a1=0.f, a2=0.f, a3=0.f;
    for (int k=0; k<512; k+=4){
      a0 += yr[k+0]*W2[(k+0)*100+c];
      a1 += yr[k+1]*W2[(k+1)*100+c];
      a2 += yr[k+2]*W2[(k+2)*100+c];
      a3 += yr[k+3]*W2[(k+3)*100+c];
    }
    out[r*100+c] = b2[c] + ((a0+a1)+(a2+a3));
  }
}

extern "C" void kernel_launch(void* const* d_in, const int* in_sizes, int n_in,
                              void* d_out, int out_size, void* d_ws, size_t ws_size,
                              hipStream_t stream)
{
  const float* feat   = (const float*)d_in[0];
  const float* prompt = (const float*)d_in[1];
  const int*   src    = (const int*)d_in[2];
  const int*   dst    = (const int*)d_in[3];
  const int*   gids   = (const int*)d_in[4];
  const float* W0  = (const float*)d_in[5];
  const float* b0  = (const float*)d_in[6];
  const float* W1  = (const float*)d_in[7];
  const float* b1  = (const float*)d_in[8];
  const float* Wp  = (const float*)d_in[9];
  const float* bp  = (const float*)d_in[10];
  const float* Wm0 = (const float*)d_in[11];
  const float* bm0 = (const float*)d_in[12];
  const float* g0  = (const float*)d_in[13];
  const float* be0 = (const float*)d_in[14];
  const float* Wm1 = (const float*)d_in[15];
  const float* bm1 = (const float*)d_in[16];
  const float* g1  = (const float*)d_in[17];
  const float* be1 = (const float*)d_in[18];
  const float* Wm2 = (const float*)d_in[19];
  const float* bm2 = (const float*)d_in[20];
  float* out = (float*)d_out;

  char* p = (char*)d_ws;
  auto carve = [&](size_t bytes) -> void* {
    void* r = (void*)p;
    p += (bytes + 255) & ~(size_t)255;
    return r;
  };
  int*   deg    = (int*)carve((size_t)Nn*4);
  int*   rowptr = (int*)carve((size_t)(Nn+1)*4);
  int*   bsum   = (int*)carve(256*4);
  int*   boff   = (int*)carve(256*4);
  int*   gCnt   = (int*)carve(256*4);
  int*   eidx   = (int*)carve((size_t)Ee*4);
  float* x1     = (float*)carve((size_t)Nn*6*4);
  unsigned short* h1  = (unsigned short*)carve((size_t)Nn*128*2);
  unsigned short* xb  = (unsigned short*)carve((size_t)Nn*128*2);
  unsigned short* W1p = (unsigned short*)carve((size_t)128*512*2);
  float* xmlp   = (float*)carve((size_t)Bb*XD*4);
  float* y0     = (float*)carve((size_t)Bb*1024*4);
  float* y1     = (float*)carve((size_t)Bb*512*4);

  // aliases onto dead regions:
  // bins: 131*13312*8B = 13.95 MB into h1 (25.6MB; h1 first written AFTER k_sort)
  // Zp0/Zp1: split-K partials into eidx/x1 (dead once the head runs)
  int2*  bins = (int2*)h1;
  float* Zp0 = (float*)eidx;
  float* Zp1 = (float*)x1;

  hipMemsetAsync(gCnt, 0, 256*4, stream);
  hipMemsetAsync(xmlp, 0, (size_t)Bb*XD*4, stream);

  k_packW<<<32, 256, 0, stream>>>(W1, W1p);

  k_bin2<<<NBIN_BLKS, 256, 0, stream>>>(src, dst, gCnt, bins);
  k_deg<<<NBINS2, 256, 0, stream>>>(bins, gCnt, deg);
  k_scanA<<<SCAN_NB, 256, 0, stream>>>(deg, bsum);
  k_scanB<<<1, 256, 0, stream>>>(bsum, boff, rowptr + Nn, SCAN_NB);
  k_scanC<<<SCAN_NB, 256, 0, stream>>>(deg, boff, rowptr);
  k_sort<<<NBINS2, 256, 0, stream>>>(bins, gCnt, rowptr, eidx);

  k_gin1<<<(Nn+255)/256, 256, 0, stream>>>(feat, rowptr, eidx, x1);
  k_gin1mlp<<<Nn/2, 256, 0, stream>>>(x1, W0, b0, h1);

  k_gather2<<<(Nn*16+255)/256, 256, 0, stream>>>(h1, rowptr, eidx, xb);
  dim3 g2((Nn+127)/128, 4);
  k_gin2m<<<g2, 256, 0, stream>>>(xb, W1p, b1, gids, xmlp);

  k_pr<<<1, 256, 0, stream>>>(prompt, Wp, bp, xmlp);

  // MLP head: split-K GEMM + fused BN/ReLU reduce
  dim3 gl0(1024/256, 8, (XD + KC - 1)/KC);      // (4, 8, 5)
  k_lin<<<gl0, 256, 0, stream>>>(xmlp, Wm0, Zp0, XD, 1024);
  k_bnrelu<<<1024/8, 256, 0, stream>>>(Zp0, bm0, g0, be0, y0, 1024, (XD + KC - 1)/KC);

  dim3 gl1(512/256, 8, 1024/KC);                // (2, 8, 8)
  k_lin<<<gl1, 256, 0, stream>>>(y0, Wm1, Zp1, 1024, 512);
  k_bnrelu<<<512/8, 256, 0, stream>>>(Zp1, bm1, g1, be1, y1, 512, 1024/KC);

  k_out<<<Bb, 128, 0, stream>>>(y1, Wm2, bm2, out);
}